// Round 1
// baseline (1730.231 us; speedup 1.0000x reference)
//
#include <hip/hip_runtime.h>

constexpr int N_NODES = 100000;
constexpr int N_EDGES = 1600000;
constexpr int FDIM = 64;
constexpr int HDIM = 36;
constexpr int CDIM = 32;

// ---------------- graph preprocessing ----------------

__global__ void hist_kernel(const int* __restrict__ ei, int* __restrict__ deg,
                            int* __restrict__ cnt) {
    int e = blockIdx.x * blockDim.x + threadIdx.x;
    int stride = gridDim.x * blockDim.x;
    for (; e < N_EDGES; e += stride) {
        int s = ei[e];
        int d = ei[N_EDGES + e];
        atomicAdd(&deg[s], 1);
        atomicAdd(&cnt[d], 1);
    }
}

__global__ void dis_kernel(const int* __restrict__ deg, float* __restrict__ dis) {
    int i = blockIdx.x * blockDim.x + threadIdx.x;
    if (i < N_NODES) {
        int d = deg[i];
        dis[i] = d > 0 ? rsqrtf((float)d) : 0.f;
    }
}

__global__ void scan1_kernel(const int* __restrict__ cnt, int* __restrict__ rp,
                             int* __restrict__ bsum) {
    __shared__ int sm[256];
    int i = blockIdx.x * 256 + threadIdx.x;
    int v = (i < N_NODES) ? cnt[i] : 0;
    sm[threadIdx.x] = v;
    __syncthreads();
    for (int off = 1; off < 256; off <<= 1) {
        int t = (threadIdx.x >= off) ? sm[threadIdx.x - off] : 0;
        __syncthreads();
        sm[threadIdx.x] += t;
        __syncthreads();
    }
    if (i < N_NODES) rp[i] = sm[threadIdx.x] - v;   // exclusive
    if (threadIdx.x == 255) bsum[blockIdx.x] = sm[255];
}

__global__ void scan2_kernel(int* __restrict__ bsum, int nb) {
    __shared__ int sm[512];
    int t = threadIdx.x;
    int v = (t < nb) ? bsum[t] : 0;
    sm[t] = v;
    __syncthreads();
    for (int off = 1; off < 512; off <<= 1) {
        int u = (t >= off) ? sm[t - off] : 0;
        __syncthreads();
        sm[t] += u;
        __syncthreads();
    }
    if (t < nb) bsum[t] = sm[t] - v;  // exclusive over block sums
}

__global__ void scan3_kernel(int* __restrict__ rp, const int* __restrict__ bsum) {
    int i = blockIdx.x * 256 + threadIdx.x;
    if (i < N_NODES) rp[i] += bsum[blockIdx.x];
    if (i == 0) rp[N_NODES] = N_EDGES;
}

__global__ void fill_kernel(const int* __restrict__ ei, const int* __restrict__ rp,
                            int* __restrict__ cur, const float* __restrict__ dis,
                            int* __restrict__ csrc, float* __restrict__ cw) {
    int e = blockIdx.x * blockDim.x + threadIdx.x;
    int stride = gridDim.x * blockDim.x;
    for (; e < N_EDGES; e += stride) {
        int s = ei[e], d = ei[N_EDGES + e];
        int pos = rp[d] + atomicAdd(&cur[d], 1);
        csrc[pos] = s;
        cw[pos] = -dis[s] * dis[d];
    }
}

// ---------------- SpMM (CSR by dst, atomic-free) ----------------
// MODE 0: OUT = L*IN    MODE 1: OUT = 2*L*IN - SUB    MODE 2: OUT = IN[i] + sum IN[src]

template <int MODE>
__global__ __launch_bounds__(256) void spmm64_kernel(
    const int* __restrict__ rp, const int* __restrict__ csrc,
    const float* __restrict__ cw, const float* __restrict__ IN,
    const float* __restrict__ SUB, float* __restrict__ OUT) {
    int row = blockIdx.x * 16 + (threadIdx.x >> 4);
    int c = threadIdx.x & 15;
    if (row >= N_NODES) return;
    int beg = rp[row], end = rp[row + 1];
    const float4* IN4 = (const float4*)IN;
    float ax = 0, ay = 0, az = 0, aw = 0;
    for (int j = beg; j < end; ++j) {
        int s = csrc[j];
        float4 v = IN4[s * 16 + c];
        if (MODE == 2) { ax += v.x; ay += v.y; az += v.z; aw += v.w; }
        else {
            float w = cw[j];
            ax = fmaf(w, v.x, ax); ay = fmaf(w, v.y, ay);
            az = fmaf(w, v.z, az); aw = fmaf(w, v.w, aw);
        }
    }
    float4 o;
    if (MODE == 1) {
        float4 s4 = ((const float4*)SUB)[row * 16 + c];
        o.x = 2.f * ax - s4.x; o.y = 2.f * ay - s4.y;
        o.z = 2.f * az - s4.z; o.w = 2.f * aw - s4.w;
    } else if (MODE == 2) {
        float4 xv = IN4[row * 16 + c];
        o.x = ax + xv.x; o.y = ay + xv.y; o.z = az + xv.z; o.w = aw + xv.w;
    } else {
        o.x = ax; o.y = ay; o.z = az; o.w = aw;
    }
    ((float4*)OUT)[row * 16 + c] = o;
}

template <int MODE>
__global__ __launch_bounds__(256) void spmm36_kernel(
    const int* __restrict__ rp, const int* __restrict__ csrc,
    const float* __restrict__ cw, const float* __restrict__ IN,
    const float* __restrict__ SUB, float* __restrict__ OUT) {
    int t = threadIdx.x;            // blockDim = 252 -> 28 rows x 9 lanes
    int row = blockIdx.x * 28 + t / 9;
    int c = t % 9;
    if (row >= N_NODES) return;
    int beg = rp[row], end = rp[row + 1];
    const float4* IN4 = (const float4*)IN;
    float ax = 0, ay = 0, az = 0, aw = 0;
    for (int j = beg; j < end; ++j) {
        int s = csrc[j];
        float4 v = IN4[s * 9 + c];
        float w = cw[j];
        ax = fmaf(w, v.x, ax); ay = fmaf(w, v.y, ay);
        az = fmaf(w, v.z, az); aw = fmaf(w, v.w, aw);
    }
    float4 o;
    if (MODE == 1) {
        float4 s4 = ((const float4*)SUB)[row * 9 + c];
        o.x = 2.f * ax - s4.x; o.y = 2.f * ay - s4.y;
        o.z = 2.f * az - s4.z; o.w = 2.f * aw - s4.w;
    } else {
        o.x = ax; o.y = ay; o.z = az; o.w = aw;
    }
    ((float4*)OUT)[row * 9 + c] = o;
}

// ---------------- small GEMM: C[N,HO] (=|+=) A[N,FI] @ W[FI,HO] (+bias, relu) ---------

template <int FI, int HO, bool RELU, bool ACCUM>
__global__ __launch_bounds__(256) void gemm_kernel(
    const float* __restrict__ A, const float* __restrict__ W,
    const float* __restrict__ bias, float* __restrict__ C) {
    constexpr int CPT = HO / 4;
    __shared__ float Wl[FI * HO];
    __shared__ float Al[64][FI + 1];
    int tid = threadIdx.x;
    for (int i = tid; i < FI * HO; i += 256) Wl[i] = W[i];
    int r0 = blockIdx.x * 64;
    for (int i = tid; i < 64 * FI; i += 256) {
        int r = i / FI, f = i % FI;
        int row = r0 + r;
        Al[r][f] = (row < N_NODES) ? A[row * FI + f] : 0.f;
    }
    __syncthreads();
    int r = tid >> 2, q = tid & 3;
    int row = r0 + r;
    if (row >= N_NODES) return;
    float acc[CPT];
#pragma unroll
    for (int j = 0; j < CPT; ++j) {
        if (ACCUM) acc[j] = C[row * HO + q * CPT + j];
        else       acc[j] = bias[q * CPT + j];
    }
#pragma unroll 4
    for (int f = 0; f < FI; ++f) {
        float a = Al[r][f];
#pragma unroll
        for (int j = 0; j < CPT; ++j)
            acc[j] = fmaf(a, Wl[f * HO + q * CPT + j], acc[j]);
    }
#pragma unroll
    for (int j = 0; j < CPT; ++j) {
        float v = acc[j];
        if (RELU) v = fmaxf(v, 0.f);
        C[row * HO + q * CPT + j] = v;
    }
}

// ---------------- BN ----------------

__global__ void stats_kernel(const float* __restrict__ Y, float* __restrict__ sums) {
    __shared__ float ls[36], lq[36];
    int tid = threadIdx.x;                 // blockDim = 288 = 8 x 36
    int g = tid / 36, c = tid % 36;
    if (tid < 36) { ls[tid] = 0.f; lq[tid] = 0.f; }
    __syncthreads();
    float s = 0.f, q = 0.f;
    for (int r = blockIdx.x * 8 + g; r < N_NODES; r += gridDim.x * 8) {
        float v = Y[r * 36 + c];
        s += v; q += v * v;
    }
    atomicAdd(&ls[c], s);
    atomicAdd(&lq[c], q);
    __syncthreads();
    if (tid < 36) {
        atomicAdd(&sums[tid], ls[tid]);
        atomicAdd(&sums[36 + tid], lq[tid]);
    }
}

__global__ void bnfin_kernel(const float* __restrict__ sums, const float* __restrict__ g,
                             const float* __restrict__ be, float* __restrict__ ss) {
    int c = threadIdx.x;
    if (c < 36) {
        float m = sums[c] / (float)N_NODES;
        float v = sums[36 + c] / (float)N_NODES - m * m;
        float sc = g[c] * rsqrtf(v + 1e-5f);
        ss[c] = sc;
        ss[36 + c] = be[c] - m * sc;
    }
}

template <bool RELU>
__global__ void bnapply_kernel(const float* __restrict__ Y, const float* __restrict__ ss,
                               float* __restrict__ OUT) {
    int idx = blockIdx.x * blockDim.x + threadIdx.x;   // over N*9 float4
    if (idx >= N_NODES * 9) return;
    float4 v = ((const float4*)Y)[idx];
    int base = (idx * 4) % 36;
    float4 o;
    o.x = fmaf(ss[base + 0], v.x, ss[36 + base + 0]);
    o.y = fmaf(ss[base + 1], v.y, ss[36 + base + 1]);
    o.z = fmaf(ss[base + 2], v.z, ss[36 + base + 2]);
    o.w = fmaf(ss[base + 3], v.w, ss[36 + base + 3]);
    if (RELU) {
        o.x = fmaxf(o.x, 0.f); o.y = fmaxf(o.y, 0.f);
        o.z = fmaxf(o.z, 0.f); o.w = fmaxf(o.w, 0.f);
    }
    ((float4*)OUT)[idx] = o;
}

// ---------------- launch ----------------

extern "C" void kernel_launch(void* const* d_in, const int* in_sizes, int n_in,
                              void* d_out, int out_size, void* d_ws, size_t ws_size,
                              hipStream_t stream) {
    const float* x      = (const float*)d_in[0];
    const int*   ei     = (const int*)d_in[1];
    const float* W1_1   = (const float*)d_in[2];
    const float* b1_1   = (const float*)d_in[3];
    const float* g1_1   = (const float*)d_in[4];
    const float* be1_1  = (const float*)d_in[5];
    const float* W1_2   = (const float*)d_in[6];
    const float* b1_2   = (const float*)d_in[7];
    const float* g1_2   = (const float*)d_in[8];
    const float* be1_2  = (const float*)d_in[9];
    const float* gin_w1 = (const float*)d_in[10];
    const float* gin_b1 = (const float*)d_in[11];
    const float* gin_w2 = (const float*)d_in[12];
    const float* gin_b2 = (const float*)d_in[13];
    const float* g2     = (const float*)d_in[14];
    const float* be2    = (const float*)d_in[15];
    const float* W4     = (const float*)d_in[16];
    const float* b4     = (const float*)d_in[17];
    float* out = (float*)d_out;

    char* ws = (char*)d_ws;
    size_t off = 0;
    auto alloc = [&](size_t bytes) -> char* {
        char* p = ws + off;
        off = (off + bytes + 255) & ~(size_t)255;
        return p;
    };
    int*   deg   = (int*)alloc((size_t)N_NODES * 4);
    int*   cnt   = (int*)alloc((size_t)N_NODES * 4);
    int*   cur   = (int*)alloc((size_t)N_NODES * 4);
    int*   rp    = (int*)alloc((size_t)(N_NODES + 1) * 4);
    int*   bsum  = (int*)alloc(512 * 4);
    float* sumsA = (float*)alloc(72 * 4);
    float* sumsB = (float*)alloc(72 * 4);
    float* sumsC = (float*)alloc(72 * 4);
    size_t zend = off;                       // everything above must start zeroed
    float* ssA  = (float*)alloc(72 * 4);
    float* ssB  = (float*)alloc(72 * 4);
    float* ssC  = (float*)alloc(72 * 4);
    float* dis  = (float*)alloc((size_t)N_NODES * 4);
    int*   csrc = (int*)alloc((size_t)N_EDGES * 4);
    float* cwv  = (float*)alloc((size_t)N_EDGES * 4);
    float* TxA  = (float*)alloc((size_t)N_NODES * 64 * 4);
    float* TxB  = (float*)alloc((size_t)N_NODES * 64 * 4);
    float* TxC  = (float*)alloc((size_t)N_NODES * 64 * 4);
    float* acc  = (float*)alloc((size_t)N_NODES * 36 * 4);
    float* x11  = (float*)alloc((size_t)N_NODES * 36 * 4);
    float* x12  = (float*)alloc((size_t)N_NODES * 36 * 4);
    if (off > ws_size) return;  // workspace too small: bail (diagnosable via absmax == max|ref|)

    hipMemsetAsync(d_ws, 0, zend, stream);

    const int SCAN_BLKS = (N_NODES + 255) / 256;      // 391
    hist_kernel<<<2048, 256, 0, stream>>>(ei, deg, cnt);
    dis_kernel<<<SCAN_BLKS, 256, 0, stream>>>(deg, dis);
    scan1_kernel<<<SCAN_BLKS, 256, 0, stream>>>(cnt, rp, bsum);
    scan2_kernel<<<1, 512, 0, stream>>>(bsum, SCAN_BLKS);
    scan3_kernel<<<SCAN_BLKS, 256, 0, stream>>>(rp, bsum);
    fill_kernel<<<2048, 256, 0, stream>>>(ei, rp, cur, dis, csrc, cwv);

    const int GEMM_BLKS = (N_NODES + 63) / 64;        // 1563
    const int SP64_BLKS = N_NODES / 16;               // 6250
    const int SP36_BLKS = (N_NODES + 27) / 28;        // 3572
    const int APPLY_BLKS = (N_NODES * 9 + 255) / 256; // 3516

    const float* bufs[3] = {TxA, TxB, TxC};

    // ---- conv1_1 (ChebConv K=8, FI=64) ----
    gemm_kernel<64, 36, false, false><<<GEMM_BLKS, 256, 0, stream>>>(x, W1_1, b1_1, acc);
    spmm64_kernel<0><<<SP64_BLKS, 256, 0, stream>>>(rp, csrc, cwv, x, nullptr, TxA);
    gemm_kernel<64, 36, false, true><<<GEMM_BLKS, 256, 0, stream>>>(TxA, W1_1 + 2304, nullptr, acc);
    for (int k = 2; k < 8; ++k) {
        const float* in  = bufs[(k - 2) % 3];
        const float* sub = (k == 2) ? x : bufs[(k - 3) % 3];
        float* ob = (float*)bufs[(k - 1) % 3];
        spmm64_kernel<1><<<SP64_BLKS, 256, 0, stream>>>(rp, csrc, cwv, in, sub, ob);
        gemm_kernel<64, 36, false, true><<<GEMM_BLKS, 256, 0, stream>>>(ob, W1_1 + k * 2304, nullptr, acc);
    }
    stats_kernel<<<512, 288, 0, stream>>>(acc, sumsA);
    bnfin_kernel<<<1, 64, 0, stream>>>(sumsA, g1_1, be1_1, ssA);
    bnapply_kernel<true><<<APPLY_BLKS, 256, 0, stream>>>(acc, ssA, x11);

    // ---- conv1_2 (ChebConv K=8, FI=36) ----
    gemm_kernel<36, 36, false, false><<<GEMM_BLKS, 256, 0, stream>>>(x11, W1_2, b1_2, acc);
    spmm36_kernel<0><<<SP36_BLKS, 252, 0, stream>>>(rp, csrc, cwv, x11, nullptr, TxA);
    gemm_kernel<36, 36, false, true><<<GEMM_BLKS, 256, 0, stream>>>(TxA, W1_2 + 1296, nullptr, acc);
    for (int k = 2; k < 8; ++k) {
        const float* in  = bufs[(k - 2) % 3];
        const float* sub = (k == 2) ? x11 : bufs[(k - 3) % 3];
        float* ob = (float*)bufs[(k - 1) % 3];
        spmm36_kernel<1><<<SP36_BLKS, 252, 0, stream>>>(rp, csrc, cwv, in, sub, ob);
        gemm_kernel<36, 36, false, true><<<GEMM_BLKS, 256, 0, stream>>>(ob, W1_2 + k * 1296, nullptr, acc);
    }
    stats_kernel<<<512, 288, 0, stream>>>(acc, sumsB);
    bnfin_kernel<<<1, 64, 0, stream>>>(sumsB, g1_2, be1_2, ssB);
    bnapply_kernel<true><<<APPLY_BLKS, 256, 0, stream>>>(acc, ssB, x12);

    // ---- GIN ----
    spmm64_kernel<2><<<SP64_BLKS, 256, 0, stream>>>(rp, csrc, cwv, x, nullptr, TxA);   // h = x + agg
    gemm_kernel<64, 36, true, false><<<GEMM_BLKS, 256, 0, stream>>>(TxA, gin_w1, gin_b1, TxB);
    gemm_kernel<36, 36, true, false><<<GEMM_BLKS, 256, 0, stream>>>(TxB, gin_w2, gin_b2, acc);
    stats_kernel<<<512, 288, 0, stream>>>(acc, sumsC);
    bnfin_kernel<<<1, 64, 0, stream>>>(sumsC, g2, be2, ssC);
    bnapply_kernel<false><<<APPLY_BLKS, 256, 0, stream>>>(acc, ssC, TxC);              // x2

    // ---- final: out = x11@W4[0:36] + x12@W4[36:72] + x2@W4[72:108] + b4 ----
    gemm_kernel<36, 32, false, false><<<GEMM_BLKS, 256, 0, stream>>>(x11, W4, b4, out);
    gemm_kernel<36, 32, false, true><<<GEMM_BLKS, 256, 0, stream>>>(x12, W4 + 36 * 32, nullptr, out);
    gemm_kernel<36, 32, false, true><<<GEMM_BLKS, 256, 0, stream>>>(TxC, W4 + 72 * 32, nullptr, out);
}

// Round 2
// 1669.275 us; speedup vs baseline: 1.0365x; 1.0365x over previous
//
#include <hip/hip_runtime.h>

constexpr int N_NODES = 100000;
constexpr int N_EDGES = 1600000;
constexpr int N_CHUNK = 8;
constexpr int CHUNK_E = N_EDGES / N_CHUNK;   // 200000

// ---------------- graph preprocessing ----------------
// 8-way privatized histograms: copy c = blockIdx&7 counts exactly edge chunk c.
// If block->XCD is round-robin (typical), each copy's atomics stay in one L2.

__global__ void hist8_kernel(const int* __restrict__ ei, int* __restrict__ deg8,
                             int* __restrict__ cnt8) {
    int c = blockIdx.x & 7;
    int lb = blockIdx.x >> 3;                 // 256 local blocks per chunk
    int* dg = deg8 + c * N_NODES;
    int* ct = cnt8 + c * N_NODES;
    int e_end = (c + 1) * CHUNK_E;
    for (int e = c * CHUNK_E + lb * 256 + threadIdx.x; e < e_end; e += 256 * 256) {
        int s = ei[e];
        int d = ei[N_EDGES + e];
        atomicAdd(&dg[s], 1);
        atomicAdd(&ct[d], 1);
    }
}

__global__ void scan1_kernel(const int* __restrict__ cnt8, const int* __restrict__ deg8,
                             int* __restrict__ rp, int* __restrict__ bsum,
                             float* __restrict__ dis) {
    __shared__ int sm[256];
    int i = blockIdx.x * 256 + threadIdx.x;
    int v = 0;
    if (i < N_NODES) {
        int dv = 0;
#pragma unroll
        for (int c = 0; c < 8; ++c) {
            v += cnt8[c * N_NODES + i];
            dv += deg8[c * N_NODES + i];
        }
        dis[i] = dv > 0 ? rsqrtf((float)dv) : 0.f;
    }
    sm[threadIdx.x] = v;
    __syncthreads();
    for (int off = 1; off < 256; off <<= 1) {
        int t = (threadIdx.x >= off) ? sm[threadIdx.x - off] : 0;
        __syncthreads();
        sm[threadIdx.x] += t;
        __syncthreads();
    }
    if (i < N_NODES) rp[i] = sm[threadIdx.x] - v;   // block-local exclusive
    if (threadIdx.x == 255) bsum[blockIdx.x] = sm[255];
}

__global__ void scan2_kernel(int* __restrict__ bsum, int nb) {
    __shared__ int sm[512];
    int t = threadIdx.x;
    int v = (t < nb) ? bsum[t] : 0;
    sm[t] = v;
    __syncthreads();
    for (int off = 1; off < 512; off <<= 1) {
        int u = (t >= off) ? sm[t - off] : 0;
        __syncthreads();
        sm[t] += u;
        __syncthreads();
    }
    if (t < nb) bsum[t] = sm[t] - v;
}

__global__ void scan3_kernel(int* __restrict__ rp, const int* __restrict__ bsum,
                             const int* __restrict__ cnt8, int* __restrict__ rp8) {
    int i = blockIdx.x * 256 + threadIdx.x;
    if (i < N_NODES) {
        int base = rp[i] + bsum[blockIdx.x];
        rp[i] = base;
        int run = base;
#pragma unroll
        for (int c = 0; c < 8; ++c) {
            rp8[c * N_NODES + i] = run;
            run += cnt8[c * N_NODES + i];
        }
    }
    if (i == 0) rp[N_NODES] = N_EDGES;
}

__global__ void fill8_kernel(const int* __restrict__ ei, const int* __restrict__ rp8,
                             int* __restrict__ cur8, const float* __restrict__ dis,
                             int2* __restrict__ csrw) {
    int c = blockIdx.x & 7;
    int lb = blockIdx.x >> 3;
    const int* r8 = rp8 + c * N_NODES;
    int* cu = cur8 + c * N_NODES;
    int e_end = (c + 1) * CHUNK_E;
    for (int e = c * CHUNK_E + lb * 256 + threadIdx.x; e < e_end; e += 256 * 256) {
        int s = ei[e];
        int d = ei[N_EDGES + e];
        int pos = r8[d] + atomicAdd(&cu[d], 1);
        csrw[pos] = make_int2(s, __float_as_int(-dis[s] * dis[d]));
    }
}

// ---------------- Clenshaw SpMM (width 36, CSR by dst) ----------------
// OUT[i] = SCALE * sum_j w_j * IN[src_j]  + Y[i]  - (HAS_B2 ? B2[i] : 0)

template <int SCALE, bool HAS_B2>
__global__ __launch_bounds__(256) void spmm_clen_kernel(
    const int* __restrict__ rp, const int2* __restrict__ csrw,
    const float* __restrict__ IN, const float* __restrict__ Y,
    const float* __restrict__ B2, float* __restrict__ OUT) {
    int t = threadIdx.x;                      // 252 threads = 28 rows x 9 lanes
    int row = blockIdx.x * 28 + t / 9;
    int c = t % 9;
    if (row >= N_NODES) return;
    int beg = rp[row], end = rp[row + 1];
    const float4* IN4 = (const float4*)IN;
    float ax = 0, ay = 0, az = 0, aw = 0;
    for (int j = beg; j < end; ++j) {
        int2 e = csrw[j];
        float w = __int_as_float(e.y);
        float4 v = IN4[e.x * 9 + c];
        ax = fmaf(w, v.x, ax); ay = fmaf(w, v.y, ay);
        az = fmaf(w, v.z, az); aw = fmaf(w, v.w, aw);
    }
    const float S = (float)SCALE;
    float4 y = ((const float4*)Y)[row * 9 + c];
    float4 o;
    o.x = fmaf(S, ax, y.x); o.y = fmaf(S, ay, y.y);
    o.z = fmaf(S, az, y.z); o.w = fmaf(S, aw, y.w);
    if (HAS_B2) {
        float4 b = ((const float4*)B2)[row * 9 + c];
        o.x -= b.x; o.y -= b.y; o.z -= b.z; o.w -= b.w;
    }
    ((float4*)OUT)[row * 9 + c] = o;
}

// GIN aggregation: H[i] = X[i] + sum_{e:dst=i} X[src_e]   (width 64)
__global__ __launch_bounds__(256) void gin_agg_kernel(
    const int* __restrict__ rp, const int2* __restrict__ csrw,
    const float* __restrict__ X, float* __restrict__ H) {
    int row = blockIdx.x * 16 + (threadIdx.x >> 4);
    int c = threadIdx.x & 15;
    if (row >= N_NODES) return;
    int beg = rp[row], end = rp[row + 1];
    const float4* X4 = (const float4*)X;
    float ax = 0, ay = 0, az = 0, aw = 0;
    for (int j = beg; j < end; ++j) {
        int2 e = csrw[j];
        float4 v = X4[e.x * 16 + c];
        ax += v.x; ay += v.y; az += v.z; aw += v.w;
    }
    float4 xv = X4[row * 16 + c];
    float4 o = {ax + xv.x, ay + xv.y, az + xv.z, aw + xv.w};
    ((float4*)H)[row * 16 + c] = o;
}

// ---------------- small GEMM: C[N,HO] = A[N,FI] @ W[FI,HO] (+bias/relu) --------
// INIT: 0 = zero-init, 1 = bias-init

template <int FI, int HO, bool RELU, int INIT>
__global__ __launch_bounds__(256) void gemm_kernel(
    const float* __restrict__ A, const float* __restrict__ W,
    const float* __restrict__ bias, float* __restrict__ C) {
    constexpr int CPT = HO / 4;
    __shared__ float Wl[FI * HO];
    __shared__ float Al[64][FI + 1];
    int tid = threadIdx.x;
    for (int i = tid; i < FI * HO; i += 256) Wl[i] = W[i];
    int r0 = blockIdx.x * 64;
    for (int i = tid; i < 64 * FI; i += 256) {
        int r = i / FI, f = i % FI;
        int row = r0 + r;
        Al[r][f] = (row < N_NODES) ? A[row * FI + f] : 0.f;
    }
    __syncthreads();
    int r = tid >> 2, q = tid & 3;
    int row = r0 + r;
    if (row >= N_NODES) return;
    float acc[CPT];
#pragma unroll
    for (int j = 0; j < CPT; ++j)
        acc[j] = (INIT == 1) ? bias[q * CPT + j] : 0.f;
#pragma unroll 4
    for (int f = 0; f < FI; ++f) {
        float a = Al[r][f];
#pragma unroll
        for (int j = 0; j < CPT; ++j)
            acc[j] = fmaf(a, Wl[f * HO + q * CPT + j], acc[j]);
    }
#pragma unroll
    for (int j = 0; j < CPT; ++j) {
        float v = acc[j];
        if (RELU) v = fmaxf(v, 0.f);
        C[row * HO + q * CPT + j] = v;
    }
}

// final: out[N,32] = x11@W4[0:36] + x12@W4[36:72] + x2@W4[72:108] + b4
__global__ __launch_bounds__(256) void fused3_kernel(
    const float* __restrict__ x11, const float* __restrict__ x12,
    const float* __restrict__ x2, const float* __restrict__ W,
    const float* __restrict__ b, float* __restrict__ out) {
    __shared__ float Wl[108 * 32];
    __shared__ float Al[64][109];
    int tid = threadIdx.x;
    for (int i = tid; i < 108 * 32; i += 256) Wl[i] = W[i];
    int r0 = blockIdx.x * 64;
    for (int i = tid; i < 64 * 108; i += 256) {
        int r = i / 108, f = i % 108;
        int row = r0 + r;
        float v = 0.f;
        if (row < N_NODES)
            v = (f < 36) ? x11[row * 36 + f]
              : (f < 72) ? x12[row * 36 + f - 36]
                         : x2[row * 36 + f - 72];
        Al[r][f] = v;
    }
    __syncthreads();
    int r = tid >> 2, q = tid & 3;
    int row = r0 + r;
    if (row >= N_NODES) return;
    float acc[8];
#pragma unroll
    for (int j = 0; j < 8; ++j) acc[j] = b[q * 8 + j];
    for (int f = 0; f < 108; ++f) {
        float a = Al[r][f];
#pragma unroll
        for (int j = 0; j < 8; ++j)
            acc[j] = fmaf(a, Wl[f * 32 + q * 8 + j], acc[j]);
    }
#pragma unroll
    for (int j = 0; j < 8; ++j) out[row * 32 + q * 8 + j] = acc[j];
}

// ---------------- BN ----------------

__global__ void stats_kernel(const float* __restrict__ Y, float* __restrict__ sums) {
    __shared__ float ls[36], lq[36];
    int tid = threadIdx.x;                 // blockDim = 288 = 8 x 36
    int g = tid / 36, c = tid % 36;
    if (tid < 36) { ls[tid] = 0.f; lq[tid] = 0.f; }
    __syncthreads();
    float s = 0.f, q = 0.f;
    for (int r = blockIdx.x * 8 + g; r < N_NODES; r += gridDim.x * 8) {
        float v = Y[r * 36 + c];
        s += v; q += v * v;
    }
    atomicAdd(&ls[c], s);
    atomicAdd(&lq[c], q);
    __syncthreads();
    if (tid < 36) {
        atomicAdd(&sums[tid], ls[tid]);
        atomicAdd(&sums[36 + tid], lq[tid]);
    }
}

__global__ void bnfin_kernel(const float* __restrict__ sums, const float* __restrict__ g,
                             const float* __restrict__ be, float* __restrict__ ss) {
    int c = threadIdx.x;
    if (c < 36) {
        float m = sums[c] / (float)N_NODES;
        float v = sums[36 + c] / (float)N_NODES - m * m;
        float sc = g[c] * rsqrtf(v + 1e-5f);
        ss[c] = sc;
        ss[36 + c] = be[c] - m * sc;
    }
}

template <bool RELU>
__global__ void bnapply_kernel(const float* __restrict__ Y, const float* __restrict__ ss,
                               float* __restrict__ OUT) {
    int idx = blockIdx.x * blockDim.x + threadIdx.x;   // over N*9 float4
    if (idx >= N_NODES * 9) return;
    float4 v = ((const float4*)Y)[idx];
    int base = (idx * 4) % 36;
    float4 o;
    o.x = fmaf(ss[base + 0], v.x, ss[36 + base + 0]);
    o.y = fmaf(ss[base + 1], v.y, ss[36 + base + 1]);
    o.z = fmaf(ss[base + 2], v.z, ss[36 + base + 2]);
    o.w = fmaf(ss[base + 3], v.w, ss[36 + base + 3]);
    if (RELU) {
        o.x = fmaxf(o.x, 0.f); o.y = fmaxf(o.y, 0.f);
        o.z = fmaxf(o.z, 0.f); o.w = fmaxf(o.w, 0.f);
    }
    ((float4*)OUT)[idx] = o;
}

// ---------------- launch ----------------

extern "C" void kernel_launch(void* const* d_in, const int* in_sizes, int n_in,
                              void* d_out, int out_size, void* d_ws, size_t ws_size,
                              hipStream_t stream) {
    const float* x      = (const float*)d_in[0];
    const int*   ei     = (const int*)d_in[1];
    const float* W1_1   = (const float*)d_in[2];
    // d_in[3] = b1_1: cancels exactly under training-mode BN (per-column bias
    // shifts the mean by the same amount) -> dropped. Same for b1_2.
    const float* g1_1   = (const float*)d_in[4];
    const float* be1_1  = (const float*)d_in[5];
    const float* W1_2   = (const float*)d_in[6];
    const float* g1_2   = (const float*)d_in[8];
    const float* be1_2  = (const float*)d_in[9];
    const float* gin_w1 = (const float*)d_in[10];
    const float* gin_b1 = (const float*)d_in[11];
    const float* gin_w2 = (const float*)d_in[12];
    const float* gin_b2 = (const float*)d_in[13];
    const float* g2     = (const float*)d_in[14];
    const float* be2    = (const float*)d_in[15];
    const float* W4     = (const float*)d_in[16];
    const float* b4     = (const float*)d_in[17];
    float* out = (float*)d_out;

    char* ws = (char*)d_ws;
    size_t off = 0;
    auto alloc = [&](size_t bytes) -> char* {
        char* p = ws + off;
        off = (off + bytes + 255) & ~(size_t)255;
        return p;
    };
    // zeroed-at-start region (one memset): cnt8, deg8, sums
    int*   cnt8  = (int*)alloc((size_t)8 * N_NODES * 4);
    int*   deg8  = (int*)alloc((size_t)8 * N_NODES * 4);   // reused as cur8 later
    float* sumsA = (float*)alloc(72 * 4);
    float* sumsB = (float*)alloc(72 * 4);
    float* sumsC = (float*)alloc(72 * 4);
    size_t zend = off;
    int*   rp    = (int*)alloc((size_t)(N_NODES + 1) * 4);
    int*   rp8   = (int*)alloc((size_t)8 * N_NODES * 4);
    int*   bsum  = (int*)alloc(512 * 4);
    float* dis   = (float*)alloc((size_t)N_NODES * 4);
    int2*  csrw  = (int2*)alloc((size_t)N_EDGES * 8);
    float* ssA   = (float*)alloc(72 * 4);
    float* ssB   = (float*)alloc(72 * 4);
    float* ssC   = (float*)alloc(72 * 4);
    // seven [N,36] rotating buffers; P0+Ptmp contiguous so they alias GIN's [N,64] H
    constexpr size_t NB36 = (size_t)N_NODES * 36 * 4;      // 14,400,000 (256-mult.)
    float* P0   = (float*)alloc(NB36);
    float* Ptmp = (float*)alloc(NB36);
    float* P1   = (float*)alloc(NB36);
    float* P2   = (float*)alloc(NB36);
    float* P3   = (float*)alloc(NB36);
    float* x11  = (float*)alloc(NB36);
    float* x12  = (float*)alloc(NB36);
    float* H    = P0;                                      // [N,64] over P0..Ptmp
    if (off > ws_size) return;  // workspace too small

    hipMemsetAsync(d_ws, 0, zend, stream);

    const int SCAN_BLKS = (N_NODES + 255) / 256;      // 391
    hist8_kernel<<<2048, 256, 0, stream>>>(ei, deg8, cnt8);
    scan1_kernel<<<SCAN_BLKS, 256, 0, stream>>>(cnt8, deg8, rp, bsum, dis);
    scan2_kernel<<<1, 512, 0, stream>>>(bsum, SCAN_BLKS);
    scan3_kernel<<<SCAN_BLKS, 256, 0, stream>>>(rp, bsum, cnt8, rp8);
    hipMemsetAsync(deg8, 0, (size_t)8 * N_NODES * 4, stream);   // deg8 -> cur8
    fill8_kernel<<<2048, 256, 0, stream>>>(ei, rp8, deg8, dis, csrw);

    const int GEMM_BLKS = (N_NODES + 63) / 64;        // 1563
    const int SP36_BLKS = (N_NODES + 27) / 28;        // 3572
    const int SP64_BLKS = N_NODES / 16;               // 6250
    const int APPLY_BLKS = (N_NODES * 9 + 255) / 256; // 3516

    // ---- conv1_1: Clenshaw, y_k = x @ W1_1[k] computed lazily into Ptmp ----
    // b7=y7(P0); b6=y6+2Lb7(P1); b5(P2); b4(P3); b3(P1); b2(P2); b1(P3);
    // S = y0 + L b1 - b2 -> P1
    gemm_kernel<64, 36, false, 0><<<GEMM_BLKS, 256, 0, stream>>>(x, W1_1 + 7 * 2304, nullptr, P0);
    gemm_kernel<64, 36, false, 0><<<GEMM_BLKS, 256, 0, stream>>>(x, W1_1 + 6 * 2304, nullptr, Ptmp);
    spmm_clen_kernel<2, false><<<SP36_BLKS, 252, 0, stream>>>(rp, csrw, P0, Ptmp, nullptr, P1);
    gemm_kernel<64, 36, false, 0><<<GEMM_BLKS, 256, 0, stream>>>(x, W1_1 + 5 * 2304, nullptr, Ptmp);
    spmm_clen_kernel<2, true><<<SP36_BLKS, 252, 0, stream>>>(rp, csrw, P1, Ptmp, P0, P2);
    gemm_kernel<64, 36, false, 0><<<GEMM_BLKS, 256, 0, stream>>>(x, W1_1 + 4 * 2304, nullptr, Ptmp);
    spmm_clen_kernel<2, true><<<SP36_BLKS, 252, 0, stream>>>(rp, csrw, P2, Ptmp, P1, P3);
    gemm_kernel<64, 36, false, 0><<<GEMM_BLKS, 256, 0, stream>>>(x, W1_1 + 3 * 2304, nullptr, Ptmp);
    spmm_clen_kernel<2, true><<<SP36_BLKS, 252, 0, stream>>>(rp, csrw, P3, Ptmp, P2, P1);
    gemm_kernel<64, 36, false, 0><<<GEMM_BLKS, 256, 0, stream>>>(x, W1_1 + 2 * 2304, nullptr, Ptmp);
    spmm_clen_kernel<2, true><<<SP36_BLKS, 252, 0, stream>>>(rp, csrw, P1, Ptmp, P3, P2);
    gemm_kernel<64, 36, false, 0><<<GEMM_BLKS, 256, 0, stream>>>(x, W1_1 + 1 * 2304, nullptr, Ptmp);
    spmm_clen_kernel<2, true><<<SP36_BLKS, 252, 0, stream>>>(rp, csrw, P2, Ptmp, P1, P3);
    gemm_kernel<64, 36, false, 0><<<GEMM_BLKS, 256, 0, stream>>>(x, W1_1 + 0 * 2304, nullptr, Ptmp);
    spmm_clen_kernel<1, true><<<SP36_BLKS, 252, 0, stream>>>(rp, csrw, P3, Ptmp, P2, P1);
    stats_kernel<<<512, 288, 0, stream>>>(P1, sumsA);
    bnfin_kernel<<<1, 64, 0, stream>>>(sumsA, g1_1, be1_1, ssA);
    bnapply_kernel<true><<<APPLY_BLKS, 256, 0, stream>>>(P1, ssA, x11);

    // ---- conv1_2: same with x11, W1_2 (stride 1296) ----
    gemm_kernel<36, 36, false, 0><<<GEMM_BLKS, 256, 0, stream>>>(x11, W1_2 + 7 * 1296, nullptr, P0);
    gemm_kernel<36, 36, false, 0><<<GEMM_BLKS, 256, 0, stream>>>(x11, W1_2 + 6 * 1296, nullptr, Ptmp);
    spmm_clen_kernel<2, false><<<SP36_BLKS, 252, 0, stream>>>(rp, csrw, P0, Ptmp, nullptr, P1);
    gemm_kernel<36, 36, false, 0><<<GEMM_BLKS, 256, 0, stream>>>(x11, W1_2 + 5 * 1296, nullptr, Ptmp);
    spmm_clen_kernel<2, true><<<SP36_BLKS, 252, 0, stream>>>(rp, csrw, P1, Ptmp, P0, P2);
    gemm_kernel<36, 36, false, 0><<<GEMM_BLKS, 256, 0, stream>>>(x11, W1_2 + 4 * 1296, nullptr, Ptmp);
    spmm_clen_kernel<2, true><<<SP36_BLKS, 252, 0, stream>>>(rp, csrw, P2, Ptmp, P1, P3);
    gemm_kernel<36, 36, false, 0><<<GEMM_BLKS, 256, 0, stream>>>(x11, W1_2 + 3 * 1296, nullptr, Ptmp);
    spmm_clen_kernel<2, true><<<SP36_BLKS, 252, 0, stream>>>(rp, csrw, P3, Ptmp, P2, P1);
    gemm_kernel<36, 36, false, 0><<<GEMM_BLKS, 256, 0, stream>>>(x11, W1_2 + 2 * 1296, nullptr, Ptmp);
    spmm_clen_kernel<2, true><<<SP36_BLKS, 252, 0, stream>>>(rp, csrw, P1, Ptmp, P3, P2);
    gemm_kernel<36, 36, false, 0><<<GEMM_BLKS, 256, 0, stream>>>(x11, W1_2 + 1 * 1296, nullptr, Ptmp);
    spmm_clen_kernel<2, true><<<SP36_BLKS, 252, 0, stream>>>(rp, csrw, P2, Ptmp, P1, P3);
    gemm_kernel<36, 36, false, 0><<<GEMM_BLKS, 256, 0, stream>>>(x11, W1_2 + 0 * 1296, nullptr, Ptmp);
    spmm_clen_kernel<1, true><<<SP36_BLKS, 252, 0, stream>>>(rp, csrw, P3, Ptmp, P2, P1);
    stats_kernel<<<512, 288, 0, stream>>>(P1, sumsB);
    bnfin_kernel<<<1, 64, 0, stream>>>(sumsB, g1_2, be1_2, ssB);
    bnapply_kernel<true><<<APPLY_BLKS, 256, 0, stream>>>(P1, ssB, x12);

    // ---- GIN ----
    gin_agg_kernel<<<SP64_BLKS, 256, 0, stream>>>(rp, csrw, x, H);
    gemm_kernel<64, 36, true, 1><<<GEMM_BLKS, 256, 0, stream>>>(H, gin_w1, gin_b1, P2);
    gemm_kernel<36, 36, true, 1><<<GEMM_BLKS, 256, 0, stream>>>(P2, gin_w2, gin_b2, P3);
    stats_kernel<<<512, 288, 0, stream>>>(P3, sumsC);
    bnfin_kernel<<<1, 64, 0, stream>>>(sumsC, g2, be2, ssC);
    bnapply_kernel<false><<<APPLY_BLKS, 256, 0, stream>>>(P3, ssC, P1);   // x2 -> P1

    // ---- final fused concat GEMM ----
    fused3_kernel<<<GEMM_BLKS, 256, 0, stream>>>(x11, x12, P1, W4, b4, out);
}